// Round 1
// baseline (145.644 us; speedup 1.0000x reference)
//
#include <hip/hip_runtime.h>
#include <math.h>

#define NTOK 198
#define CCH  192
#define DIMV 8

__device__ __forceinline__ float qgelu(float v) {
    // x * sigmoid(1.702 x)
    return v / (1.0f + __expf(-1.702f * v));
}

__global__ __launch_bounds__(256) void convpass_fused(
    const float* __restrict__ x,       // [B,198,192]
    const float* __restrict__ w_down,  // [8,192]
    const float* __restrict__ b_down,  // [8]
    const float* __restrict__ conv_w,  // [8,8,3,3]
    const float* __restrict__ conv_b,  // [8]
    const float* __restrict__ w_up,    // [192,8]
    const float* __restrict__ b_up,    // [192]
    float* __restrict__ out)           // [B,198,192]
{
    const int b   = blockIdx.x;
    const int tid = threadIdx.x;

    __shared__ float s_x[32 * 196];   // 25088 B x-tile (stride 196: bank-spread + 16B aligned)
    __shared__ float s_wdn[8 * 196];  // 6272 B w_down staged (stride 196)
    __shared__ float s_d[NTOK * 9];   // 7128 B down-proj+gelu output (stride 9)

    // Aliases into the x-tile region (dead after phase A):
    float* s_d2 = s_x;                // 198*8 = 1584 floats, stride 8 (16B-aligned rows)
    float* s_cw = s_x + NTOK * 8;     // 576 floats conv weights

    // ---- stage w_down (before first chunk's compute; barrier below covers it)
    for (int t = tid; t < 8 * 192; t += 256) {
        int dim = t / 192, c = t % 192;
        s_wdn[dim * 196 + c] = w_down[t];
    }

    // ================= Phase A: d = qgelu(x @ w_down^T + b_down) =================
    const float* xb = x + (size_t)b * NTOK * CCH;
    for (int ch = 0; ch < 7; ++ch) {
        const int n0   = ch * 32;
        const int ntok = min(32, NTOK - n0);
        __syncthreads();  // prev chunk's compute done (iter0: nothing to wait except w_dn later)
        // coalesced float4 load of ntok rows into LDS
        const int nf4 = ntok * 48;
        for (int t = tid; t < nf4; t += 256) {
            int row = t / 48, c4 = t % 48;
            float4 v = *(const float4*)(xb + (size_t)(n0 + row) * CCH + c4 * 4);
            *(float4*)(&s_x[row * 196 + c4 * 4]) = v;
        }
        __syncthreads();  // tile + w_dn ready
        if (tid < ntok * 8) {
            const int nl  = tid >> 3;
            const int dim = tid & 7;
            float acc = b_down[dim];
            const float4* xr = (const float4*)(&s_x[nl * 196]);
            const float4* wr = (const float4*)(&s_wdn[dim * 196]);
            #pragma unroll 8
            for (int c4 = 0; c4 < 48; ++c4) {
                float4 xv = xr[c4];
                float4 wv = wr[c4];
                acc += xv.x * wv.x + xv.y * wv.y + xv.z * wv.z + xv.w * wv.w;
            }
            s_d[(n0 + nl) * 9 + dim] = qgelu(acc);
        }
    }
    __syncthreads();  // s_d complete; s_x free

    // stage conv weights into alias region
    for (int t = tid; t < 576; t += 256) s_cw[t] = conv_w[t];
    __syncthreads();

    // ================= Phase B: 3x3 conv + gelu -> s_d2 =================
    for (int j = tid; j < 1584; j += 256) {
        if (j < 1568) {
            const int pos = j >> 3, o = j & 7;
            const int h = pos / 14, w = pos % 14;
            float acc = conv_b[o];
            #pragma unroll
            for (int dh = -1; dh <= 1; ++dh) {
                const int hh = h + dh;
                if (hh < 0 || hh > 13) continue;
                #pragma unroll
                for (int dw = -1; dw <= 1; ++dw) {
                    const int ww = w + dw;
                    if (ww < 0 || ww > 13) continue;
                    const int tok = 2 + hh * 14 + ww;
                    const int k   = (dh + 1) * 3 + (dw + 1);
                    #pragma unroll
                    for (int i = 0; i < 8; ++i)
                        acc += s_d[tok * 9 + i] * s_cw[(o * 8 + i) * 9 + k];
                }
            }
            s_d2[(2 + pos) * 8 + o] = qgelu(acc);
        } else if (j < 1576) {
            const int o = j - 1568;  // cls token: only center tap
            float acc = conv_b[o];
            #pragma unroll
            for (int i = 0; i < 8; ++i)
                acc += s_d[0 * 9 + i] * s_cw[(o * 8 + i) * 9 + 4];
            s_d2[0 * 8 + o] = qgelu(acc);
        } else {
            const int o = j - 1576;  // dist token replaced by zeros; qgelu(0)=0
            s_d2[1 * 8 + o] = 0.0f;
        }
    }
    __syncthreads();

    // ================= Phase C: out = d2 @ w_up^T + b_up =================
    if (tid < 240) {
        const int c4    = tid % 48;   // owns channels c4*4 .. c4*4+3
        const int n_off = tid / 48;   // 0..4
        float w_r[4][8];
        #pragma unroll
        for (int cc = 0; cc < 4; ++cc) {
            float4 wa = *(const float4*)(w_up + (c4 * 4 + cc) * 8);
            float4 wb = *(const float4*)(w_up + (c4 * 4 + cc) * 8 + 4);
            w_r[cc][0] = wa.x; w_r[cc][1] = wa.y; w_r[cc][2] = wa.z; w_r[cc][3] = wa.w;
            w_r[cc][4] = wb.x; w_r[cc][5] = wb.y; w_r[cc][6] = wb.z; w_r[cc][7] = wb.w;
        }
        const float4 bu = *(const float4*)(b_up + c4 * 4);
        float* outb = out + (size_t)b * NTOK * CCH;
        for (int n = n_off; n < NTOK; n += 5) {
            const float4 da = *(const float4*)(&s_d2[n * 8]);
            const float4 db = *(const float4*)(&s_d2[n * 8 + 4]);
            float accs[4] = {bu.x, bu.y, bu.z, bu.w};
            #pragma unroll
            for (int cc = 0; cc < 4; ++cc) {
                accs[cc] += da.x * w_r[cc][0] + da.y * w_r[cc][1]
                          + da.z * w_r[cc][2] + da.w * w_r[cc][3]
                          + db.x * w_r[cc][4] + db.y * w_r[cc][5]
                          + db.z * w_r[cc][6] + db.w * w_r[cc][7];
            }
            float4 r = {accs[0], accs[1], accs[2], accs[3]};
            *(float4*)(outb + (size_t)n * CCH + c4 * 4) = r;
        }
    }
}

extern "C" void kernel_launch(void* const* d_in, const int* in_sizes, int n_in,
                              void* d_out, int out_size, void* d_ws, size_t ws_size,
                              hipStream_t stream) {
    const float* x      = (const float*)d_in[0];
    const float* w_down = (const float*)d_in[1];
    const float* b_down = (const float*)d_in[2];
    const float* conv_w = (const float*)d_in[3];
    const float* conv_b = (const float*)d_in[4];
    const float* w_up   = (const float*)d_in[5];
    const float* b_up   = (const float*)d_in[6];
    float* out = (float*)d_out;

    const int B = 1024;
    convpass_fused<<<dim3(B), dim3(256), 0, stream>>>(
        x, w_down, b_down, conv_w, conv_b, w_up, b_up, out);
}